// Round 5
// baseline (285.403 us; speedup 1.0000x reference)
//
#include <hip/hip_runtime.h>
#include <math.h>

// Problem constants
#define NREL 499        // 2*MAX_LEN-1
#define NREL_PAD 500    // row stride for qrel (2000 B, 16-B aligned)
#define LDT 72          // bf16 LDS row stride (gemm tiles)
#define KVB 128         // flash j-tile
#define LDK 72          // Ks stride [128 j][64 d + pad]
#define LDV 136         // Vs stride [64 d][128 j + pad]
#define LDP 136         // QPs stride (Q [64][64], later P [64][128])

typedef __attribute__((ext_vector_type(8))) short bf16x8;
typedef __attribute__((ext_vector_type(4))) float f32x4;

__device__ __forceinline__ float bf2f(ushort x) {
  union { unsigned u; float f; } v; v.u = ((unsigned)x) << 16; return v.f;
}
__device__ __forceinline__ ushort f2bf(float x) {
  union { float f; unsigned u; } v; v.f = x;
  return (ushort)((v.u + 0x8000u) >> 16);
}
__device__ __forceinline__ bf16x8 pack8(float4 a, float4 b) {
  bf16x8 r;
  r[0] = (short)f2bf(a.x); r[1] = (short)f2bf(a.y);
  r[2] = (short)f2bf(a.z); r[3] = (short)f2bf(a.w);
  r[4] = (short)f2bf(b.x); r[5] = (short)f2bf(b.y);
  r[6] = (short)f2bf(b.z); r[7] = (short)f2bf(b.w);
  return r;
}

// ============================================================================
// cast_bf16: q/k/v fp32 [4096][512] -> bf16, contiguous dst. Grid (1024,1,3).
// ============================================================================
__global__ __launch_bounds__(256) void cast_bf16(const float* __restrict__ q,
                                                 const float* __restrict__ k,
                                                 const float* __restrict__ v,
                                                 ushort* __restrict__ dst) {
  const int z = blockIdx.z;
  const float* src = (z == 0) ? q : (z == 1) ? k : v;
  const size_t base = ((size_t)blockIdx.x * 256 + threadIdx.x) * 8;
  float4 a = *(const float4*)(src + base);
  float4 b = *(const float4*)(src + base + 4);
  *(bf16x8*)(dst + (size_t)z * 2097152 + base) = pack8(a, b);
}

// ============================================================================
// prep_wt: Wt[z][n][k] (bf16) = W_z[k][n], z = {q,k,v,o}. Grid (8,8,4).
// Blocks (0,0,z) additionally build maskbf[b][j] = mask ? 1.0bf : 0.0bf.
// ============================================================================
__global__ __launch_bounds__(256) void prep_wt(const float* __restrict__ W0,
                                               const float* __restrict__ W1,
                                               const float* __restrict__ W2,
                                               const float* __restrict__ W3,
                                               const int* __restrict__ mask,
                                               ushort* __restrict__ Wt,
                                               ushort* __restrict__ maskbf) {
  __shared__ float T[64][68];
  const int t = threadIdx.x;
  const int k0 = blockIdx.x * 64, n0 = blockIdx.y * 64, z = blockIdx.z;
  const float* W = (z == 0) ? W0 : (z == 1) ? W1 : (z == 2) ? W2 : W3;
#pragma unroll
  for (int s = 0; s < 4; ++s) {
    int idx = t + s * 256;
    int r = idx >> 4, c4 = (idx & 15) << 2;
    *(float4*)&T[r][c4] = *(const float4*)(W + (size_t)(k0 + r) * 512 + n0 + c4);
  }
  if (blockIdx.x == 0 && blockIdx.y == 0) {
    int base = z * 1024 + t * 4;
    int4 mv = *(const int4*)(mask + base);
    ushort4 mo;
    mo.x = mv.x ? 0x3F80 : 0; mo.y = mv.y ? 0x3F80 : 0;
    mo.z = mv.z ? 0x3F80 : 0; mo.w = mv.w ? 0x3F80 : 0;
    *(ushort4*)(maskbf + base) = mo;
  }
  __syncthreads();
#pragma unroll
  for (int s = 0; s < 4; ++s) {
    int idx = t + s * 256;
    int row = idx >> 4, c4 = (idx & 15) << 2;  // row = n_local, c4 = k_local
    ushort4 u = make_ushort4(f2bf(T[c4 + 0][row]), f2bf(T[c4 + 1][row]),
                             f2bf(T[c4 + 2][row]), f2bf(T[c4 + 3][row]));
    *(ushort4*)(Wt + (size_t)z * 262144 + (size_t)(n0 + row) * 512 + k0 + c4) = u;
  }
}

// ============================================================================
// gemm_tile_body: C[64x64 tile] = A(bf16 [M][512]) @ Wt^T(bf16 [n][k]) + bias.
// LDS-staged (padded stride), register-held next tile, 8 K-steps of BK=64.
// MODE 0: fp32 row-major out [4096][512]               (output projection)
// MODE 1: bf16 Vt [bh][64 d][2048 l], masked columns zeroed (mvec)
// MODE 2: bf16 row-major head-split [bh][2048 l][64 d], scaled by oscale
// ============================================================================
template <int MODE>
__device__ __forceinline__ void gemm_tile_body(const ushort* __restrict__ A,
                                               const ushort* __restrict__ Wt,
                                               const float* __restrict__ bias,
                                               const int* __restrict__ mvec,
                                               void* __restrict__ outv,
                                               int bx, int by, float oscale) {
  __shared__ ushort As[64 * LDT];
  __shared__ ushort Bs[64 * LDT];
  const int t = threadIdx.x;
  const int lane = t & 63, wave = t >> 6;
  const int m16 = lane & 15, quad = lane >> 4;
  const int koff = quad << 3;
  const int i0 = by * 64, n0 = bx * 64;
  const int row0 = t >> 3, off0 = (t & 7) << 3;
  const int row1 = (t + 256) >> 3, off1 = ((t + 256) & 7) << 3;
  const ushort* Ab = A + (size_t)i0 * 512;
  const ushort* Bb = Wt + (size_t)n0 * 512;

  uint4 ar0 = *(const uint4*)(Ab + (size_t)row0 * 512 + off0);
  uint4 ar1 = *(const uint4*)(Ab + (size_t)row1 * 512 + off1);
  uint4 br0 = *(const uint4*)(Bb + (size_t)row0 * 512 + off0);
  uint4 br1 = *(const uint4*)(Bb + (size_t)row1 * 512 + off1);

  f32x4 acc[4] = {{0.f, 0.f, 0.f, 0.f}, {0.f, 0.f, 0.f, 0.f},
                  {0.f, 0.f, 0.f, 0.f}, {0.f, 0.f, 0.f, 0.f}};

  for (int ks = 0; ks < 8; ++ks) {
    __syncthreads();
    *(uint4*)&As[row0 * LDT + off0] = ar0;
    *(uint4*)&As[row1 * LDT + off1] = ar1;
    *(uint4*)&Bs[row0 * LDT + off0] = br0;
    *(uint4*)&Bs[row1 * LDT + off1] = br1;
    __syncthreads();

    const int kn = ((ks + 1) & 7) << 6;
    uint4 an0 = *(const uint4*)(Ab + (size_t)row0 * 512 + kn + off0);
    uint4 an1 = *(const uint4*)(Ab + (size_t)row1 * 512 + kn + off1);
    uint4 bn0 = *(const uint4*)(Bb + (size_t)row0 * 512 + kn + off0);
    uint4 bn1 = *(const uint4*)(Bb + (size_t)row1 * 512 + kn + off1);

    __builtin_amdgcn_s_setprio(1);
    if (MODE != 1) {
#pragma unroll
      for (int kh = 0; kh < 2; ++kh) {
        bf16x8 af = *(const bf16x8*)&As[((wave << 4) + m16) * LDT + (kh << 5) + koff];
#pragma unroll
        for (int nt = 0; nt < 4; ++nt) {
          bf16x8 wf = *(const bf16x8*)&Bs[((nt << 4) + m16) * LDT + (kh << 5) + koff];
          acc[nt] = __builtin_amdgcn_mfma_f32_16x16x32_bf16(af, wf, acc[nt], 0, 0, 0);
        }
      }
    } else {
#pragma unroll
      for (int kh = 0; kh < 2; ++kh) {
        bf16x8 wf = *(const bf16x8*)&Bs[((wave << 4) + m16) * LDT + (kh << 5) + koff];
#pragma unroll
        for (int it = 0; it < 4; ++it) {
          bf16x8 af = *(const bf16x8*)&As[((it << 4) + m16) * LDT + (kh << 5) + koff];
          acc[it] = __builtin_amdgcn_mfma_f32_16x16x32_bf16(wf, af, acc[it], 0, 0, 0);
        }
      }
    }
    __builtin_amdgcn_s_setprio(0);

    ar0 = an0; ar1 = an1; br0 = bn0; br1 = bn1;
  }

  if (MODE == 0) {
    float* out = (float*)outv;
#pragma unroll
    for (int nt = 0; nt < 4; ++nt) {
      float bn = bias[n0 + (nt << 4) + m16];
#pragma unroll
      for (int r = 0; r < 4; ++r) {
        int i = i0 + (wave << 4) + (quad << 2) + r;
        out[(size_t)i * 512 + n0 + (nt << 4) + m16] = acc[nt][r] + bn;
      }
    }
  } else if (MODE == 2) {
    ushort* out = (ushort*)outv;
    const int b = i0 >> 11, l0 = i0 & 2047, h = n0 >> 6;
#pragma unroll
    for (int nt = 0; nt < 4; ++nt) {
      float bn = bias[n0 + (nt << 4) + m16];
      int d = (nt << 4) + m16;
#pragma unroll
      for (int r = 0; r < 4; ++r) {
        int il = (wave << 4) + (quad << 2) + r;
        out[((size_t)(b * 8 + h) * 2048 + l0 + il) * 64 + d] =
            f2bf((acc[nt][r] + bn) * oscale);
      }
    }
  } else {  // MODE 1: Vt [bh][d][l], masked columns -> 0
    ushort* out = (ushort*)outv;
    const int b = i0 >> 11, l0 = i0 & 2047, h = n0 >> 6;
    float4 b4 = *(const float4*)(bias + n0 + (wave << 4) + (quad << 2));
    float bb[4] = {b4.x, b4.y, b4.z, b4.w};
    float mkf[4];
#pragma unroll
    for (int it = 0; it < 4; ++it)
      mkf[it] = (mvec[b * 2048 + l0 + (it << 4) + m16] != 0) ? 1.f : 0.f;
#pragma unroll
    for (int r = 0; r < 4; ++r) {
      int d = (wave << 4) + (quad << 2) + r;
#pragma unroll
      for (int it = 0; it < 4; ++it) {
        out[((size_t)(b * 8 + h) * 64 + d) * 2048 + l0 + (it << 4) + m16] =
            f2bf((acc[it][r] + bb[r]) * mkf[it]);
      }
    }
  }
}

template <int MODE>
__global__ __launch_bounds__(256) void gemm_tile(const ushort* __restrict__ A,
                                                 const ushort* __restrict__ Wt,
                                                 const float* __restrict__ bias,
                                                 void* __restrict__ outv) {
  gemm_tile_body<MODE>(A, Wt, bias, nullptr, outv, blockIdx.x, blockIdx.y, 1.f);
}

// Merged QKV projection: grid (8, 64, 3). Q output pre-scaled by 0.125
// (power-of-2, exact in bf16) so flash needs no post-QK scale; rel table is
// pre-scaled by 8 in qrel_mfma so qrel values are bitwise unchanged.
__global__ __launch_bounds__(256) void gemm_qkv(
    const ushort* __restrict__ Abf, const ushort* __restrict__ Wt,
    const float* __restrict__ bq, const float* __restrict__ bk,
    const float* __restrict__ bv, const int* __restrict__ mask,
    ushort* __restrict__ Qw, ushort* __restrict__ Kw, ushort* __restrict__ Vtw) {
  const int z = blockIdx.z;
  if (z == 0) {
    gemm_tile_body<2>(Abf, Wt, bq, nullptr, (void*)Qw, blockIdx.x, blockIdx.y,
                      0.125f);
  } else if (z == 1) {
    gemm_tile_body<2>(Abf + 2097152, Wt + 262144, bk, nullptr, (void*)Kw,
                      blockIdx.x, blockIdx.y, 1.f);
  } else {
    gemm_tile_body<1>(Abf + 2 * 2097152, Wt + 2 * 262144, bv, mask, (void*)Vtw,
                      blockIdx.x, blockIdx.y, 1.f);
  }
}

// ============================================================================
// qrel_mfma: qrel[bh][i][r] = sum_d Q[bh][i][d]*rel[r][d] (fp32, stride
// NREL_PAD). Q is pre-scaled by 1/8, rel scaled here by 8 -> identical values.
// ============================================================================
__global__ __launch_bounds__(256) void qrel_mfma(const ushort* __restrict__ Qw,
                                                 const float* __restrict__ rel,
                                                 float* __restrict__ qrel) {
  const int t = threadIdx.x;
  const int lane = t & 63, wave = t >> 6;
  const int m16 = lane & 15, quad = lane >> 4;
  const int r0 = blockIdx.x * 64;
  const int i0 = blockIdx.y * 64;
  const int bh = blockIdx.z;
  const ushort* Qb = Qw + ((size_t)bh * 2048 + i0 + (wave << 4) + m16) * 64;
  bf16x8 qa0 = *(const bf16x8*)(Qb + (quad << 3));
  bf16x8 qa1 = *(const bf16x8*)(Qb + 32 + (quad << 3));

  f32x4 acc[4] = {{0.f, 0.f, 0.f, 0.f}, {0.f, 0.f, 0.f, 0.f},
                  {0.f, 0.f, 0.f, 0.f}, {0.f, 0.f, 0.f, 0.f}};
#pragma unroll
  for (int rt = 0; rt < 4; ++rt) {
    int rr = min(r0 + (rt << 4) + m16, NREL - 1);
    const float* rp = rel + (size_t)rr * 64 + (quad << 3);
    float4 a0 = *(const float4*)rp,        a1 = *(const float4*)(rp + 4);
    float4 a2 = *(const float4*)(rp + 32), a3 = *(const float4*)(rp + 36);
    a0.x *= 8.f; a0.y *= 8.f; a0.z *= 8.f; a0.w *= 8.f;
    a1.x *= 8.f; a1.y *= 8.f; a1.z *= 8.f; a1.w *= 8.f;
    a2.x *= 8.f; a2.y *= 8.f; a2.z *= 8.f; a2.w *= 8.f;
    a3.x *= 8.f; a3.y *= 8.f; a3.z *= 8.f; a3.w *= 8.f;
    bf16x8 rf0 = pack8(a0, a1);
    bf16x8 rf1 = pack8(a2, a3);
    acc[rt] = __builtin_amdgcn_mfma_f32_16x16x32_bf16(qa0, rf0, acc[rt], 0, 0, 0);
    acc[rt] = __builtin_amdgcn_mfma_f32_16x16x32_bf16(qa1, rf1, acc[rt], 0, 0, 0);
  }
#pragma unroll
  for (int rt = 0; rt < 4; ++rt) {
    int r = r0 + (rt << 4) + m16;
    if (r < NREL_PAD) {
#pragma unroll
      for (int rg = 0; rg < 4; ++rg) {
        int i = i0 + (wave << 4) + (quad << 2) + rg;
        qrel[((size_t)bh * 2048 + i) * NREL_PAD + r] = acc[rt][rg];
      }
    }
  }
}

// ============================================================================
// qrel gather for one 128-j tile; wave-uniform clamp shortcut.
// ============================================================================
__device__ __forceinline__ void gather_qv(float qv[8][4],
                                          const float* __restrict__ qrow,
                                          int iq, int iw0, int j0, int quad) {
  if (j0 - iw0 >= 264) {  // j - i >= 249 for all pairs -> rr = 498
    float e = qrow[NREL - 1];
#pragma unroll
    for (int jt = 0; jt < 8; ++jt)
#pragma unroll
      for (int r = 0; r < 4; ++r) qv[jt][r] = e;
  } else if (iw0 - j0 >= 376) {  // i - j >= 249 for all pairs -> rr = 0
    float e = qrow[0];
#pragma unroll
    for (int jt = 0; jt < 8; ++jt)
#pragma unroll
      for (int r = 0; r < 4; ++r) qv[jt][r] = e;
  } else {
#pragma unroll
    for (int jt = 0; jt < 8; ++jt) {
#pragma unroll
      for (int r = 0; r < 4; ++r) {
        int j = j0 + (jt << 4) + (quad << 2) + r;
        int rr = min(NREL - 1, max(0, j - iq + 249));
        qv[jt][r] = qrow[rr];
      }
    }
  }
}

// ============================================================================
// Flash attention, MFMA bf16, swapped-operand QK^T, KVB=128:
//  - rel-bias folded into MFMA C-init (Q pre-scaled 1/8 -> no score FMA);
//  - defer-max (THR=8): rescale only when the running max actually grows;
//  - XCD-aware block swizzle: 64 consecutive remapped blocks (2 heads,
//    1 MB K/V) per XCD -> K/V prefetch hits private L2.
// ============================================================================
__global__ __launch_bounds__(256) void flash_attn(
    const ushort* __restrict__ Qw, const ushort* __restrict__ Kw,
    const ushort* __restrict__ Vt, const float* __restrict__ qrel,
    const ushort* __restrict__ maskbf, ushort* __restrict__ attnbf) {
  __shared__ ushort QPs[64 * LDP];  // Q tile [i][d]; later P [i][j]
  __shared__ ushort Ks[KVB * LDK];  // [j][d]
  __shared__ ushort Vs[64 * LDV];   // [d][j]
  const int t = threadIdx.x;
  const int lane = t & 63, wave = t >> 6;
  const int m16 = lane & 15, quad = lane >> 4;
  const int koff = quad << 3;
  const int bid = (blockIdx.y << 5) + blockIdx.x;
  const int swz = ((bid & 7) << 6) + (bid >> 3);  // XCD-contiguous chunks
  const int i0 = (swz & 31) << 6;
  const int bh = swz >> 5;
  const int b = bh >> 3, h = bh & 7;
  const ushort* Qb = Qw + (size_t)bh * 2048 * 64;
  const ushort* Kb = Kw + (size_t)bh * 2048 * 64;
  const ushort* Vb = Vt + (size_t)bh * 64 * 2048;
  const ushort* mbf = maskbf + b * 2048;
  const int iw0 = i0 + (wave << 4);
  const int iq = iw0 + m16;  // this lane's output row
  const float* qrow = qrel + ((size_t)bh * 2048 + iq) * NREL_PAD;

  // staging coords
  const int krow = t >> 3, kcol = (t & 7) << 3;    // K: rows +32/step, 4 steps
  const int vrow = t >> 4, vcol = (t & 15) << 3;   // V: rows +16/step, 4 steps

  // Q tile -> LDS (2 chunks)
  *(uint4*)&QPs[krow * LDP + kcol] =
      *(const uint4*)(Qb + (size_t)(i0 + krow) * 64 + kcol);
  *(uint4*)&QPs[(krow + 32) * LDP + kcol] =
      *(const uint4*)(Qb + (size_t)(i0 + krow + 32) * 64 + kcol);
  __syncthreads();

  bf16x8 qa0 = *(const bf16x8*)&QPs[((wave << 4) + m16) * LDP + koff];
  bf16x8 qa1 = *(const bf16x8*)&QPs[((wave << 4) + m16) * LDP + 32 + koff];

  // ---- prologue prefetch for j0 = 0 ----
  uint4 kr[4], vr[4];
#pragma unroll
  for (int s = 0; s < 4; ++s) {
    kr[s] = *(const uint4*)(Kb + (size_t)(krow + s * 32) * 64 + kcol);
    vr[s] = *(const uint4*)(Vb + (size_t)(vrow + s * 16) * 2048 + vcol);
  }
  float qv[8][4];
  gather_qv(qv, qrow, iq, iw0, 0, quad);

  float m_i = -INFINITY;
  f32x4 oacc[4];
  f32x4 lacc = {0.f, 0.f, 0.f, 0.f};
#pragma unroll
  for (int dt = 0; dt < 4; ++dt) oacc[dt] = (f32x4){0.f, 0.f, 0.f, 0.f};

  for (int j0 = 0; j0 < 2048; j0 += KVB) {
    __syncthreads();
#pragma unroll
    for (int s = 0; s < 4; ++s) {
      *(uint4*)&Ks[(krow + s * 32) * LDK + kcol] = kr[s];
      *(uint4*)&Vs[(vrow + s * 16) * LDV + vcol] = vr[s];
    }
    __syncthreads();

    // ---- next-tile prefetch (hides under this iter's compute) ----
    const int jn = (j0 + KVB) & 2047;  // wraps on last iter (unused)
    uint4 kn[4], vn[4];
#pragma unroll
    for (int s = 0; s < 4; ++s) {
      kn[s] = *(const uint4*)(Kb + (size_t)(jn + krow + s * 32) * 64 + kcol);
      vn[s] = *(const uint4*)(Vb + (size_t)(vrow + s * 16) * 2048 + jn + vcol);
    }
    bf16x8 mf[4];
#pragma unroll
    for (int ks = 0; ks < 4; ++ks)
      mf[ks] = *(const bf16x8*)(mbf + j0 + (ks << 5) + koff);
    float qn[8][4];
    gather_qv(qn, qrow, iq, iw0, jn, quad);

    // ---- QK^T, swapped, bias-initialized: sacc[jt][r] = S[iq][j] ----
    f32x4 sacc[8];
    __builtin_amdgcn_s_setprio(1);
#pragma unroll
    for (int jt = 0; jt < 8; ++jt) {
      bf16x8 kb0 = *(const bf16x8*)&Ks[((jt << 4) + m16) * LDK + koff];
      bf16x8 kb1 = *(const bf16x8*)&Ks[((jt << 4) + m16) * LDK + 32 + koff];
      f32x4 z = {qv[jt][0], qv[jt][1], qv[jt][2], qv[jt][3]};
      z = __builtin_amdgcn_mfma_f32_16x16x32_bf16(kb0, qa0, z, 0, 0, 0);
      z = __builtin_amdgcn_mfma_f32_16x16x32_bf16(kb1, qa1, z, 0, 0, 0);
      sacc[jt] = z;
    }
    __builtin_amdgcn_s_setprio(0);

    // ---- row max: 32 in-register + 2 cross-quad shfl ----
    float mj[8];
#pragma unroll
    for (int jt = 0; jt < 8; ++jt)
      mj[jt] = fmaxf(fmaxf(sacc[jt][0], sacc[jt][1]),
                     fmaxf(sacc[jt][2], sacc[jt][3]));
    float mx = fmaxf(fmaxf(fmaxf(mj[0], mj[1]), fmaxf(mj[2], mj[3])),
                     fmaxf(fmaxf(mj[4], mj[5]), fmaxf(mj[6], mj[7])));
    mx = fmaxf(mx, __shfl_xor(mx, 16));
    mx = fmaxf(mx, __shfl_xor(mx, 32));

    // ---- defer-max: rescale only on real growth (P bounded by e^8) ----
    if (__any(mx > m_i + 8.f)) {
      float mnew = fmaxf(m_i, mx);
      float al = __expf(m_i - mnew);
      m_i = mnew;
#pragma unroll
      for (int dt = 0; dt < 4; ++dt)
#pragma unroll
        for (int r = 0; r < 4; ++r) oacc[dt][r] *= al;
#pragma unroll
      for (int r = 0; r < 4; ++r) lacc[r] *= al;
    }

    // ---- P = exp(S - m_i) -> LDS (per-wave region, b64 runs) ----
    const int prow = ((wave << 4) + m16) * LDP;
#pragma unroll
    for (int jt = 0; jt < 8; ++jt) {
      ushort4 pk;
      pk.x = f2bf(__expf(sacc[jt][0] - m_i));
      pk.y = f2bf(__expf(sacc[jt][1] - m_i));
      pk.z = f2bf(__expf(sacc[jt][2] - m_i));
      pk.w = f2bf(__expf(sacc[jt][3] - m_i));
      *(ushort4*)&QPs[prow + (jt << 4) + (quad << 2)] = pk;
    }
    __asm__ volatile("s_waitcnt lgkmcnt(0)" ::: "memory");

    bf16x8 pa[4];
#pragma unroll
    for (int ks = 0; ks < 4; ++ks)
      pa[ks] = *(const bf16x8*)&QPs[prow + (ks << 5) + koff];
    __builtin_amdgcn_s_setprio(1);
#pragma unroll
    for (int ks = 0; ks < 4; ++ks)
      lacc = __builtin_amdgcn_mfma_f32_16x16x32_bf16(mf[ks], pa[ks], lacc, 0, 0, 0);
#pragma unroll
    for (int dt = 0; dt < 4; ++dt) {
#pragma unroll
      for (int ks = 0; ks < 4; ++ks) {
        bf16x8 vb = *(const bf16x8*)&Vs[((dt << 4) + m16) * LDV + (ks << 5) + koff];
        oacc[dt] = __builtin_amdgcn_mfma_f32_16x16x32_bf16(vb, pa[ks], oacc[dt], 0, 0, 0);
      }
    }
    __builtin_amdgcn_s_setprio(0);

    // ---- rotate prefetched state ----
#pragma unroll
    for (int s = 0; s < 4; ++s) { kr[s] = kn[s]; vr[s] = vn[s]; }
#pragma unroll
    for (int jt = 0; jt < 8; ++jt)
#pragma unroll
      for (int r = 0; r < 4; ++r) qv[jt][r] = qn[jt][r];
  }

  // epilogue: lane holds O[iq][d = dt*16 + quad*4 + r]; l = lacc[0]
  float inv = 1.0f / lacc[0];
  ushort* dst = attnbf + (size_t)(b * 2048 + iq) * 512 + h * 64;
#pragma unroll
  for (int dt = 0; dt < 4; ++dt) {
    ushort4 st;
    st.x = f2bf(oacc[dt][0] * inv);
    st.y = f2bf(oacc[dt][1] * inv);
    st.z = f2bf(oacc[dt][2] * inv);
    st.w = f2bf(oacc[dt][3] * inv);
    *(ushort4*)(dst + (dt << 4) + (quad << 2)) = st;
  }
}

// ============================================================================
extern "C" void kernel_launch(void* const* d_in, const int* in_sizes, int n_in,
                              void* d_out, int out_size, void* d_ws,
                              size_t ws_size, hipStream_t stream) {
  const float* query = (const float*)d_in[0];
  const float* key   = (const float*)d_in[1];
  const float* value = (const float*)d_in[2];
  const int*   mask  = (const int*)d_in[3];
  const float* Wq = (const float*)d_in[4];
  const float* bq = (const float*)d_in[5];
  const float* Wk = (const float*)d_in[6];
  const float* bk = (const float*)d_in[7];
  const float* Wv = (const float*)d_in[8];
  const float* bv = (const float*)d_in[9];
  const float* Wo = (const float*)d_in[10];
  const float* bo = (const float*)d_in[11];
  const float* rel = (const float*)d_in[12];

  char* w = (char*)d_ws;
  size_t off = 0;
  ushort* Qw  = (ushort*)(w + off); off += (size_t)16 * 2048 * 64 * 2;       // 4 MB
  ushort* Kw  = (ushort*)(w + off); off += (size_t)16 * 2048 * 64 * 2;       // 4 MB
  ushort* Vtw = (ushort*)(w + off); off += (size_t)16 * 64 * 2048 * 2;       // 4 MB
  ushort* Wt  = (ushort*)(w + off); off += (size_t)4 * 512 * 512 * 2;        // 2 MB
  float* qrel = (float*)(w + off);  off += (size_t)16 * 2048 * NREL_PAD * 4; // 65.5 MB
  ushort* attnbf = (ushort*)(w + off); off += (size_t)4096 * 512 * 2;        // 4 MB
  ushort* Abf = (ushort*)(w + off); off += (size_t)3 * 4096 * 512 * 2;       // 12.6 MB
  ushort* maskbf = (ushort*)(w + off); off += (size_t)2 * 2048 * 2;          // 8 KB
  float* out = (float*)d_out;

  dim3 bb(256);
  hipLaunchKernelGGL(cast_bf16, dim3(1024, 1, 3), bb, 0, stream, query, key,
                     value, Abf);
  hipLaunchKernelGGL(prep_wt, dim3(8, 8, 4), bb, 0, stream, Wq, Wk, Wv, Wo,
                     mask, Wt, maskbf);
  hipLaunchKernelGGL(gemm_qkv, dim3(8, 64, 3), bb, 0, stream, Abf, Wt, bq, bk,
                     bv, mask, Qw, Kw, Vtw);
  hipLaunchKernelGGL(qrel_mfma, dim3(8, 32, 16), bb, 0, stream, Qw, rel, qrel);
  hipLaunchKernelGGL(flash_attn, dim3(32, 16), bb, 0, stream, Qw, Kw, Vtw, qrel,
                     maskbf, attnbf);
  hipLaunchKernelGGL((gemm_tile<0>), dim3(8, 64), bb, 0, stream, attnbf,
                     Wt + 3 * 262144, bo, (void*)out);
}

// Round 6
// 232.051 us; speedup vs baseline: 1.2299x; 1.2299x over previous
//
#include <hip/hip_runtime.h>
#include <math.h>

// Problem constants
#define NREL 499        // 2*MAX_LEN-1
#define NREL_PAD 500    // row stride for qrel (2000 B, 16-B aligned)
#define LDB 72          // bf16 LDS row stride (flash kernel)
#define LDT 72          // bf16 LDS row stride (gemm tiles)

typedef __attribute__((ext_vector_type(8))) short bf16x8;
typedef __attribute__((ext_vector_type(4))) float f32x4;

__device__ __forceinline__ float bf2f(ushort x) {
  union { unsigned u; float f; } v; v.u = ((unsigned)x) << 16; return v.f;
}
__device__ __forceinline__ ushort f2bf(float x) {
  union { float f; unsigned u; } v; v.f = x;
  return (ushort)((v.u + 0x8000u) >> 16);
}
__device__ __forceinline__ bf16x8 pack8(float4 a, float4 b) {
  bf16x8 r;
  r[0] = (short)f2bf(a.x); r[1] = (short)f2bf(a.y);
  r[2] = (short)f2bf(a.z); r[3] = (short)f2bf(a.w);
  r[4] = (short)f2bf(b.x); r[5] = (short)f2bf(b.y);
  r[6] = (short)f2bf(b.z); r[7] = (short)f2bf(b.w);
  return r;
}

// ============================================================================
// cast_bf16: q/k/v fp32 [4096][512] -> bf16, contiguous dst. Grid (1024,1,3).
// ============================================================================
__global__ __launch_bounds__(256) void cast_bf16(const float* __restrict__ q,
                                                 const float* __restrict__ k,
                                                 const float* __restrict__ v,
                                                 ushort* __restrict__ dst) {
  const int z = blockIdx.z;
  const float* src = (z == 0) ? q : (z == 1) ? k : v;
  const size_t base = ((size_t)blockIdx.x * 256 + threadIdx.x) * 8;
  float4 a = *(const float4*)(src + base);
  float4 b = *(const float4*)(src + base + 4);
  *(bf16x8*)(dst + (size_t)z * 2097152 + base) = pack8(a, b);
}

// ============================================================================
// prep_wt: Wt[z][n][k] (bf16) = W_z[k][n], z = {q,k,v,o}. Grid (8,8,4).
// Blocks (0,0,z) additionally build maskbf[b][j] = mask ? 1.0bf : 0.0bf.
// ============================================================================
__global__ __launch_bounds__(256) void prep_wt(const float* __restrict__ W0,
                                               const float* __restrict__ W1,
                                               const float* __restrict__ W2,
                                               const float* __restrict__ W3,
                                               const int* __restrict__ mask,
                                               ushort* __restrict__ Wt,
                                               ushort* __restrict__ maskbf) {
  __shared__ float T[64][68];
  const int t = threadIdx.x;
  const int k0 = blockIdx.x * 64, n0 = blockIdx.y * 64, z = blockIdx.z;
  const float* W = (z == 0) ? W0 : (z == 1) ? W1 : (z == 2) ? W2 : W3;
#pragma unroll
  for (int s = 0; s < 4; ++s) {
    int idx = t + s * 256;
    int r = idx >> 4, c4 = (idx & 15) << 2;
    *(float4*)&T[r][c4] = *(const float4*)(W + (size_t)(k0 + r) * 512 + n0 + c4);
  }
  if (blockIdx.x == 0 && blockIdx.y == 0) {
    int base = z * 1024 + t * 4;
    int4 mv = *(const int4*)(mask + base);
    ushort4 mo;
    mo.x = mv.x ? 0x3F80 : 0; mo.y = mv.y ? 0x3F80 : 0;
    mo.z = mv.z ? 0x3F80 : 0; mo.w = mv.w ? 0x3F80 : 0;
    *(ushort4*)(maskbf + base) = mo;
  }
  __syncthreads();
#pragma unroll
  for (int s = 0; s < 4; ++s) {
    int idx = t + s * 256;
    int row = idx >> 4, c4 = (idx & 15) << 2;  // row = n_local, c4 = k_local
    ushort4 u = make_ushort4(f2bf(T[c4 + 0][row]), f2bf(T[c4 + 1][row]),
                             f2bf(T[c4 + 2][row]), f2bf(T[c4 + 3][row]));
    *(ushort4*)(Wt + (size_t)z * 262144 + (size_t)(n0 + row) * 512 + k0 + c4) = u;
  }
}

// ============================================================================
// gemm_tile_body: C[64x64 tile] = A(bf16 [M][512]) @ Wt^T(bf16 [n][k]) + bias.
// LDS-staged (padded stride), register-held next tile, 8 K-steps of BK=64.
// MODE 0: fp32 row-major out [4096][512]               (output projection)
// MODE 1: bf16 Vt [bh][64 d][2048 l], masked columns zeroed (mvec)
// MODE 2: bf16 row-major head-split [bh][2048 l][64 d], scaled by oscale
// ============================================================================
template <int MODE>
__device__ __forceinline__ void gemm_tile_body(const ushort* __restrict__ A,
                                               const ushort* __restrict__ Wt,
                                               const float* __restrict__ bias,
                                               const int* __restrict__ mvec,
                                               void* __restrict__ outv,
                                               int bx, int by, float oscale) {
  __shared__ ushort As[64 * LDT];
  __shared__ ushort Bs[64 * LDT];
  const int t = threadIdx.x;
  const int lane = t & 63, wave = t >> 6;
  const int m16 = lane & 15, quad = lane >> 4;
  const int koff = quad << 3;
  const int i0 = by * 64, n0 = bx * 64;
  const int row0 = t >> 3, off0 = (t & 7) << 3;
  const int row1 = (t + 256) >> 3, off1 = ((t + 256) & 7) << 3;
  const ushort* Ab = A + (size_t)i0 * 512;
  const ushort* Bb = Wt + (size_t)n0 * 512;

  uint4 ar0 = *(const uint4*)(Ab + (size_t)row0 * 512 + off0);
  uint4 ar1 = *(const uint4*)(Ab + (size_t)row1 * 512 + off1);
  uint4 br0 = *(const uint4*)(Bb + (size_t)row0 * 512 + off0);
  uint4 br1 = *(const uint4*)(Bb + (size_t)row1 * 512 + off1);

  f32x4 acc[4] = {{0.f, 0.f, 0.f, 0.f}, {0.f, 0.f, 0.f, 0.f},
                  {0.f, 0.f, 0.f, 0.f}, {0.f, 0.f, 0.f, 0.f}};

  for (int ks = 0; ks < 8; ++ks) {
    __syncthreads();
    *(uint4*)&As[row0 * LDT + off0] = ar0;
    *(uint4*)&As[row1 * LDT + off1] = ar1;
    *(uint4*)&Bs[row0 * LDT + off0] = br0;
    *(uint4*)&Bs[row1 * LDT + off1] = br1;
    __syncthreads();

    const int kn = ((ks + 1) & 7) << 6;
    uint4 an0 = *(const uint4*)(Ab + (size_t)row0 * 512 + kn + off0);
    uint4 an1 = *(const uint4*)(Ab + (size_t)row1 * 512 + kn + off1);
    uint4 bn0 = *(const uint4*)(Bb + (size_t)row0 * 512 + kn + off0);
    uint4 bn1 = *(const uint4*)(Bb + (size_t)row1 * 512 + kn + off1);

    __builtin_amdgcn_s_setprio(1);
    if (MODE != 1) {
#pragma unroll
      for (int kh = 0; kh < 2; ++kh) {
        bf16x8 af = *(const bf16x8*)&As[((wave << 4) + m16) * LDT + (kh << 5) + koff];
#pragma unroll
        for (int nt = 0; nt < 4; ++nt) {
          bf16x8 wf = *(const bf16x8*)&Bs[((nt << 4) + m16) * LDT + (kh << 5) + koff];
          acc[nt] = __builtin_amdgcn_mfma_f32_16x16x32_bf16(af, wf, acc[nt], 0, 0, 0);
        }
      }
    } else {
#pragma unroll
      for (int kh = 0; kh < 2; ++kh) {
        bf16x8 wf = *(const bf16x8*)&Bs[((wave << 4) + m16) * LDT + (kh << 5) + koff];
#pragma unroll
        for (int it = 0; it < 4; ++it) {
          bf16x8 af = *(const bf16x8*)&As[((it << 4) + m16) * LDT + (kh << 5) + koff];
          acc[it] = __builtin_amdgcn_mfma_f32_16x16x32_bf16(wf, af, acc[it], 0, 0, 0);
        }
      }
    }
    __builtin_amdgcn_s_setprio(0);

    ar0 = an0; ar1 = an1; br0 = bn0; br1 = bn1;
  }

  if (MODE == 0) {
    float* out = (float*)outv;
#pragma unroll
    for (int nt = 0; nt < 4; ++nt) {
      float bn = bias[n0 + (nt << 4) + m16];
#pragma unroll
      for (int r = 0; r < 4; ++r) {
        int i = i0 + (wave << 4) + (quad << 2) + r;
        out[(size_t)i * 512 + n0 + (nt << 4) + m16] = acc[nt][r] + bn;
      }
    }
  } else if (MODE == 2) {
    ushort* out = (ushort*)outv;
    const int b = i0 >> 11, l0 = i0 & 2047, h = n0 >> 6;
#pragma unroll
    for (int nt = 0; nt < 4; ++nt) {
      float bn = bias[n0 + (nt << 4) + m16];
      int d = (nt << 4) + m16;
#pragma unroll
      for (int r = 0; r < 4; ++r) {
        int il = (wave << 4) + (quad << 2) + r;
        out[((size_t)(b * 8 + h) * 2048 + l0 + il) * 64 + d] =
            f2bf((acc[nt][r] + bn) * oscale);
      }
    }
  } else {  // MODE 1: Vt [bh][d][l], masked columns -> 0
    ushort* out = (ushort*)outv;
    const int b = i0 >> 11, l0 = i0 & 2047, h = n0 >> 6;
    float4 b4 = *(const float4*)(bias + n0 + (wave << 4) + (quad << 2));
    float bb[4] = {b4.x, b4.y, b4.z, b4.w};
    float mkf[4];
#pragma unroll
    for (int it = 0; it < 4; ++it)
      mkf[it] = (mvec[b * 2048 + l0 + (it << 4) + m16] != 0) ? 1.f : 0.f;
#pragma unroll
    for (int r = 0; r < 4; ++r) {
      int d = (wave << 4) + (quad << 2) + r;
#pragma unroll
      for (int it = 0; it < 4; ++it) {
        out[((size_t)(b * 8 + h) * 64 + d) * 2048 + l0 + (it << 4) + m16] =
            f2bf((acc[it][r] + bb[r]) * mkf[it]);
      }
    }
  }
}

template <int MODE>
__global__ __launch_bounds__(256) void gemm_tile(const ushort* __restrict__ A,
                                                 const ushort* __restrict__ Wt,
                                                 const float* __restrict__ bias,
                                                 void* __restrict__ outv) {
  gemm_tile_body<MODE>(A, Wt, bias, nullptr, outv, blockIdx.x, blockIdx.y, 1.f);
}

// Merged QKV projection: grid (8, 64, 3). Q output pre-scaled by 0.125
// (power-of-2, exact in bf16); rel table pre-scaled by 8 in qrel_mfma so
// qrel values are bitwise unchanged.
__global__ __launch_bounds__(256) void gemm_qkv(
    const ushort* __restrict__ Abf, const ushort* __restrict__ Wt,
    const float* __restrict__ bq, const float* __restrict__ bk,
    const float* __restrict__ bv, const int* __restrict__ mask,
    ushort* __restrict__ Qw, ushort* __restrict__ Kw, ushort* __restrict__ Vtw) {
  const int z = blockIdx.z;
  if (z == 0) {
    gemm_tile_body<2>(Abf, Wt, bq, nullptr, (void*)Qw, blockIdx.x, blockIdx.y,
                      0.125f);
  } else if (z == 1) {
    gemm_tile_body<2>(Abf + 2097152, Wt + 262144, bk, nullptr, (void*)Kw,
                      blockIdx.x, blockIdx.y, 1.f);
  } else {
    gemm_tile_body<1>(Abf + 2 * 2097152, Wt + 2 * 262144, bv, mask, (void*)Vtw,
                      blockIdx.x, blockIdx.y, 1.f);
  }
}

// ============================================================================
// qrel_mfma: qrel[bh][i][r] = sum_d Q[bh][i][d]*rel[r][d] (fp32, stride
// NREL_PAD). Q is pre-scaled by 1/8, rel scaled here by 8 -> identical values.
// ============================================================================
__global__ __launch_bounds__(256) void qrel_mfma(const ushort* __restrict__ Qw,
                                                 const float* __restrict__ rel,
                                                 float* __restrict__ qrel) {
  const int t = threadIdx.x;
  const int lane = t & 63, wave = t >> 6;
  const int m16 = lane & 15, quad = lane >> 4;
  const int r0 = blockIdx.x * 64;
  const int i0 = blockIdx.y * 64;
  const int bh = blockIdx.z;
  const ushort* Qb = Qw + ((size_t)bh * 2048 + i0 + (wave << 4) + m16) * 64;
  bf16x8 qa0 = *(const bf16x8*)(Qb + (quad << 3));
  bf16x8 qa1 = *(const bf16x8*)(Qb + 32 + (quad << 3));

  f32x4 acc[4] = {{0.f, 0.f, 0.f, 0.f}, {0.f, 0.f, 0.f, 0.f},
                  {0.f, 0.f, 0.f, 0.f}, {0.f, 0.f, 0.f, 0.f}};
#pragma unroll
  for (int rt = 0; rt < 4; ++rt) {
    int rr = min(r0 + (rt << 4) + m16, NREL - 1);
    const float* rp = rel + (size_t)rr * 64 + (quad << 3);
    float4 a0 = *(const float4*)rp,        a1 = *(const float4*)(rp + 4);
    float4 a2 = *(const float4*)(rp + 32), a3 = *(const float4*)(rp + 36);
    a0.x *= 8.f; a0.y *= 8.f; a0.z *= 8.f; a0.w *= 8.f;
    a1.x *= 8.f; a1.y *= 8.f; a1.z *= 8.f; a1.w *= 8.f;
    a2.x *= 8.f; a2.y *= 8.f; a2.z *= 8.f; a2.w *= 8.f;
    a3.x *= 8.f; a3.y *= 8.f; a3.z *= 8.f; a3.w *= 8.f;
    bf16x8 rf0 = pack8(a0, a1);
    bf16x8 rf1 = pack8(a2, a3);
    acc[rt] = __builtin_amdgcn_mfma_f32_16x16x32_bf16(qa0, rf0, acc[rt], 0, 0, 0);
    acc[rt] = __builtin_amdgcn_mfma_f32_16x16x32_bf16(qa1, rf1, acc[rt], 0, 0, 0);
  }
#pragma unroll
  for (int rt = 0; rt < 4; ++rt) {
    int r = r0 + (rt << 4) + m16;
    if (r < NREL_PAD) {
#pragma unroll
      for (int rg = 0; rg < 4; ++rg) {
        int i = i0 + (wave << 4) + (quad << 2) + rg;
        qrel[((size_t)bh * 2048 + i) * NREL_PAD + r] = acc[rt][rg];
      }
    }
  }
}

// ============================================================================
// qrel gather for one 64-j tile; wave-uniform clamp shortcut.
// ============================================================================
__device__ __forceinline__ void gather_qv(float qv[4][4],
                                          const float* __restrict__ qrow,
                                          int iq, int iw0, int j0, int quad) {
  if (j0 - iw0 >= 264) {  // j - i >= 249 for all pairs -> rr = 498
    float e = qrow[NREL - 1];
#pragma unroll
    for (int jt = 0; jt < 4; ++jt)
#pragma unroll
      for (int r = 0; r < 4; ++r) qv[jt][r] = e;
  } else if (iw0 - j0 >= 312) {  // i - j >= 249 for all pairs -> rr = 0
    float e = qrow[0];
#pragma unroll
    for (int jt = 0; jt < 4; ++jt)
#pragma unroll
      for (int r = 0; r < 4; ++r) qv[jt][r] = e;
  } else {
#pragma unroll
    for (int jt = 0; jt < 4; ++jt) {
#pragma unroll
      for (int r = 0; r < 4; ++r) {
        int j = j0 + (jt << 4) + (quad << 2) + r;
        int rr = min(NREL - 1, max(0, j - iq + 249));
        qv[jt][r] = qrow[rr];
      }
    }
  }
}

// ============================================================================
// Flash attention, MFMA bf16, swapped-operand QK^T, KVB=64 (R4's proven
// no-spill pipeline) + R5's VALU folds:
//  - rel-bias folded into MFMA C-init (Q pre-scaled 1/8, no score FMA);
//  - defer-max (THR=8): rescale only when running max actually grows;
//  - XCD-aware block swizzle (64 consecutive blocks = 2 heads per XCD).
// ============================================================================
__global__ __launch_bounds__(256) void flash_attn(
    const ushort* __restrict__ Qw, const ushort* __restrict__ Kw,
    const ushort* __restrict__ Vt, const float* __restrict__ qrel,
    const ushort* __restrict__ maskbf, ushort* __restrict__ attnbf) {
  __shared__ ushort QPs[64 * LDB];  // Q tile [i][d]; later P [i][j]
  __shared__ ushort Ks[64 * LDB];   // [j][d]
  __shared__ ushort Vs[64 * LDB];   // [d][j]
  const int t = threadIdx.x;
  const int lane = t & 63, wave = t >> 6;
  const int m16 = lane & 15, quad = lane >> 4;
  const int koff = quad << 3;
  const int bid = ((int)blockIdx.y << 5) + (int)blockIdx.x;
  const int swz = ((bid & 7) << 6) + (bid >> 3);  // XCD-contiguous chunks
  const int i0 = (swz & 31) << 6;
  const int bh = swz >> 5;
  const int b = bh >> 3, h = bh & 7;
  const ushort* Qb = Qw + (size_t)bh * 2048 * 64;
  const ushort* Kb = Kw + (size_t)bh * 2048 * 64;
  const ushort* Vb = Vt + (size_t)bh * 64 * 2048;
  const ushort* mbf = maskbf + b * 2048;
  const int iw0 = i0 + (wave << 4);
  const int iq = iw0 + m16;  // this lane's output row
  const float* qrow = qrel + ((size_t)bh * 2048 + iq) * NREL_PAD;

  const int row0 = t >> 3, off0 = (t & 7) << 3;
  const int row1 = (t + 256) >> 3, off1 = ((t + 256) & 7) << 3;

  // Q tile -> LDS
  *(uint4*)&QPs[row0 * LDB + off0] =
      *(const uint4*)(Qb + (size_t)(i0 + row0) * 64 + off0);
  *(uint4*)&QPs[row1 * LDB + off1] =
      *(const uint4*)(Qb + (size_t)(i0 + row1) * 64 + off1);
  __syncthreads();

  bf16x8 qa0 = *(const bf16x8*)&QPs[((wave << 4) + m16) * LDB + koff];
  bf16x8 qa1 = *(const bf16x8*)&QPs[((wave << 4) + m16) * LDB + 32 + koff];

  // ---- prologue prefetch for j0 = 0 ----
  uint4 kr0 = *(const uint4*)(Kb + (size_t)row0 * 64 + off0);
  uint4 kr1 = *(const uint4*)(Kb + (size_t)row1 * 64 + off1);
  uint4 vr0 = *(const uint4*)(Vb + (size_t)row0 * 2048 + off0);
  uint4 vr1 = *(const uint4*)(Vb + (size_t)row1 * 2048 + off1);
  bf16x8 mfr0 = *(const bf16x8*)(mbf + koff);
  bf16x8 mfr1 = *(const bf16x8*)(mbf + 32 + koff);
  float qv[4][4];
  gather_qv(qv, qrow, iq, iw0, 0, quad);

  float m_i = -INFINITY;
  f32x4 oacc[4];
  f32x4 lacc = {0.f, 0.f, 0.f, 0.f};
#pragma unroll
  for (int dt = 0; dt < 4; ++dt) oacc[dt] = (f32x4){0.f, 0.f, 0.f, 0.f};

  for (int j0 = 0; j0 < 2048; j0 += 64) {
    __syncthreads();
    *(uint4*)&Ks[row0 * LDB + off0] = kr0;
    *(uint4*)&Ks[row1 * LDB + off1] = kr1;
    *(uint4*)&Vs[row0 * LDB + off0] = vr0;
    *(uint4*)&Vs[row1 * LDB + off1] = vr1;
    __syncthreads();

    const int jn = (j0 + 64) & 2047;  // wraps on last iter (unused)
    uint4 kn0 = *(const uint4*)(Kb + (size_t)(jn + row0) * 64 + off0);
    uint4 kn1 = *(const uint4*)(Kb + (size_t)(jn + row1) * 64 + off1);
    uint4 vn0 = *(const uint4*)(Vb + (size_t)row0 * 2048 + jn + off0);
    uint4 vn1 = *(const uint4*)(Vb + (size_t)row1 * 2048 + jn + off1);
    bf16x8 mfn0 = *(const bf16x8*)(mbf + jn + koff);
    bf16x8 mfn1 = *(const bf16x8*)(mbf + jn + 32 + koff);
    float qn[4][4];
    gather_qv(qn, qrow, iq, iw0, jn, quad);

    // ---- QK^T, swapped, bias-initialized: sacc[jt][r] = S[iq][j] ----
    f32x4 sacc[4];
    __builtin_amdgcn_s_setprio(1);
#pragma unroll
    for (int jt = 0; jt < 4; ++jt) {
      bf16x8 kb0 = *(const bf16x8*)&Ks[((jt << 4) + m16) * LDB + koff];
      bf16x8 kb1 = *(const bf16x8*)&Ks[((jt << 4) + m16) * LDB + 32 + koff];
      f32x4 z = {qv[jt][0], qv[jt][1], qv[jt][2], qv[jt][3]};
      z = __builtin_amdgcn_mfma_f32_16x16x32_bf16(kb0, qa0, z, 0, 0, 0);
      z = __builtin_amdgcn_mfma_f32_16x16x32_bf16(kb1, qa1, z, 0, 0, 0);
      sacc[jt] = z;
    }
    __builtin_amdgcn_s_setprio(0);

    // ---- row max: in-register + 2 cross-quad shfl ----
    float t0 = fmaxf(fmaxf(sacc[0][0], sacc[0][1]), fmaxf(sacc[0][2], sacc[0][3]));
    float t1 = fmaxf(fmaxf(sacc[1][0], sacc[1][1]), fmaxf(sacc[1][2], sacc[1][3]));
    float t2 = fmaxf(fmaxf(sacc[2][0], sacc[2][1]), fmaxf(sacc[2][2], sacc[2][3]));
    float t3 = fmaxf(fmaxf(sacc[3][0], sacc[3][1]), fmaxf(sacc[3][2], sacc[3][3]));
    float mx = fmaxf(fmaxf(t0, t1), fmaxf(t2, t3));
    mx = fmaxf(mx, __shfl_xor(mx, 16));
    mx = fmaxf(mx, __shfl_xor(mx, 32));

    // ---- defer-max: rescale only on real growth (P bounded by e^8) ----
    if (__any(mx > m_i + 8.f)) {
      float mnew = fmaxf(m_i, mx);
      float al = __expf(m_i - mnew);
      m_i = mnew;
#pragma unroll
      for (int dt = 0; dt < 4; ++dt)
#pragma unroll
        for (int r = 0; r < 4; ++r) oacc[dt][r] *= al;
#pragma unroll
      for (int r = 0; r < 4; ++r) lacc[r] *= al;
    }

    // ---- P = exp(S - m_i) -> LDS (per-wave region, b64 runs) ----
    const int prow = ((wave << 4) + m16) * LDB;
#pragma unroll
    for (int jt = 0; jt < 4; ++jt) {
      ushort4 pk;
      pk.x = f2bf(__expf(sacc[jt][0] - m_i));
      pk.y = f2bf(__expf(sacc[jt][1] - m_i));
      pk.z = f2bf(__expf(sacc[jt][2] - m_i));
      pk.w = f2bf(__expf(sacc[jt][3] - m_i));
      *(ushort4*)&QPs[prow + (jt << 4) + (quad << 2)] = pk;
    }
    __asm__ volatile("s_waitcnt lgkmcnt(0)" ::: "memory");

    bf16x8 pa0 = *(const bf16x8*)&QPs[prow + koff];
    bf16x8 pa1 = *(const bf16x8*)&QPs[prow + 32 + koff];
    __builtin_amdgcn_s_setprio(1);
    lacc = __builtin_amdgcn_mfma_f32_16x16x32_bf16(mfr0, pa0, lacc, 0, 0, 0);
    lacc = __builtin_amdgcn_mfma_f32_16x16x32_bf16(mfr1, pa1, lacc, 0, 0, 0);
#pragma unroll
    for (int dt = 0; dt < 4; ++dt) {
      bf16x8 vb0 = *(const bf16x8*)&Vs[((dt << 4) + m16) * LDB + koff];
      bf16x8 vb1 = *(const bf16x8*)&Vs[((dt << 4) + m16) * LDB + 32 + koff];
      oacc[dt] = __builtin_amdgcn_mfma_f32_16x16x32_bf16(vb0, pa0, oacc[dt], 0, 0, 0);
      oacc[dt] = __builtin_amdgcn_mfma_f32_16x16x32_bf16(vb1, pa1, oacc[dt], 0, 0, 0);
    }
    __builtin_amdgcn_s_setprio(0);

    kr0 = kn0; kr1 = kn1; vr0 = vn0; vr1 = vn1;
    mfr0 = mfn0; mfr1 = mfn1;
#pragma unroll
    for (int jt = 0; jt < 4; ++jt)
#pragma unroll
      for (int r = 0; r < 4; ++r) qv[jt][r] = qn[jt][r];
  }

  // epilogue: lane holds O[iq][d = dt*16 + quad*4 + r]; l = lacc[0]
  float inv = 1.0f / lacc[0];
  ushort* dst = attnbf + (size_t)(b * 2048 + iq) * 512 + h * 64;
#pragma unroll
  for (int dt = 0; dt < 4; ++dt) {
    ushort4 st;
    st.x = f2bf(oacc[dt][0] * inv);
    st.y = f2bf(oacc[dt][1] * inv);
    st.z = f2bf(oacc[dt][2] * inv);
    st.w = f2bf(oacc[dt][3] * inv);
    *(ushort4*)(dst + (dt << 4) + (quad << 2)) = st;
  }
}

// ============================================================================
extern "C" void kernel_launch(void* const* d_in, const int* in_sizes, int n_in,
                              void* d_out, int out_size, void* d_ws,
                              size_t ws_size, hipStream_t stream) {
  const float* query = (const float*)d_in[0];
  const float* key   = (const float*)d_in[1];
  const float* value = (const float*)d_in[2];
  const int*   mask  = (const int*)d_in[3];
  const float* Wq = (const float*)d_in[4];
  const float* bq = (const float*)d_in[5];
  const float* Wk = (const float*)d_in[6];
  const float* bk = (const float*)d_in[7];
  const float* Wv = (const float*)d_in[8];
  const float* bv = (const float*)d_in[9];
  const float* Wo = (const float*)d_in[10];
  const float* bo = (const float*)d_in[11];
  const float* rel = (const float*)d_in[12];

  char* w = (char*)d_ws;
  size_t off = 0;
  ushort* Qw  = (ushort*)(w + off); off += (size_t)16 * 2048 * 64 * 2;       // 4 MB
  ushort* Kw  = (ushort*)(w + off); off += (size_t)16 * 2048 * 64 * 2;       // 4 MB
  ushort* Vtw = (ushort*)(w + off); off += (size_t)16 * 64 * 2048 * 2;       // 4 MB
  ushort* Wt  = (ushort*)(w + off); off += (size_t)4 * 512 * 512 * 2;        // 2 MB
  float* qrel = (float*)(w + off);  off += (size_t)16 * 2048 * NREL_PAD * 4; // 65.5 MB
  ushort* attnbf = (ushort*)(w + off); off += (size_t)4096 * 512 * 2;        // 4 MB
  ushort* Abf = (ushort*)(w + off); off += (size_t)3 * 4096 * 512 * 2;       // 12.6 MB
  ushort* maskbf = (ushort*)(w + off); off += (size_t)2 * 2048 * 2;          // 8 KB
  float* out = (float*)d_out;

  dim3 bb(256);
  hipLaunchKernelGGL(cast_bf16, dim3(1024, 1, 3), bb, 0, stream, query, key,
                     value, Abf);
  hipLaunchKernelGGL(prep_wt, dim3(8, 8, 4), bb, 0, stream, Wq, Wk, Wv, Wo,
                     mask, Wt, maskbf);
  hipLaunchKernelGGL(gemm_qkv, dim3(8, 64, 3), bb, 0, stream, Abf, Wt, bq, bk,
                     bv, mask, Qw, Kw, Vtw);
  hipLaunchKernelGGL(qrel_mfma, dim3(8, 32, 16), bb, 0, stream, Qw, rel, qrel);
  hipLaunchKernelGGL(flash_attn, dim3(32, 16), bb, 0, stream, Qw, Kw, Vtw, qrel,
                     maskbf, attnbf);
  hipLaunchKernelGGL((gemm_tile<0>), dim3(8, 64), bb, 0, stream, attnbf,
                     Wt + 3 * 262144, bo, (void*)out);
}